// Round 22
// baseline (98.663 us; speedup 1.0000x reference)
//
#include <hip/hip_runtime.h>
#include <hip/hip_bf16.h>
#include <cstdint>
#include <cmath>

#define DM 1024
#define NH 16
#define DK 64
#define NB 2
#define SS 2048
#define MM (NB*SS)   // 4096 rows

typedef unsigned short u16;
typedef uint32_t u32;
typedef __attribute__((ext_vector_type(4))) float f32x4;
typedef __attribute__((ext_vector_type(8))) short s16x8;
typedef __attribute__((ext_vector_type(2))) uint32_t u32x2;

__device__ __forceinline__ u16 f2bf(float f) {
    __hip_bfloat16 h = __float2bfloat16(f);
    return __builtin_bit_cast(u16, h);
}

__device__ __forceinline__ u32 cvtpk(float a, float b) {
    u32 r;
    asm("v_cvt_pk_bf16_f32 %0, %1, %2" : "=v"(r) : "v"(a), "v"(b));
    return r;
}

__device__ __forceinline__ void gload_lds16(void* lds, const void* g) {
    __builtin_amdgcn_global_load_lds(
        (const __attribute__((address_space(1))) uint32_t*)g,
        (__attribute__((address_space(3))) uint32_t*)lds, 16, 0, 0);
}

// XOR-swizzled byte offset within a [rows][128B] LDS tile: 16B slot ^= row&7.
__device__ __forceinline__ int swz(int row, int cb) {
    return row * 128 + ((((cb) >> 4) ^ (row & 7)) << 4) + ((cb) & 15);
}

#define FENCE_BAR  do { __builtin_amdgcn_sched_barrier(0); \
                        __builtin_amdgcn_s_barrier();      \
                        __builtin_amdgcn_sched_barrier(0); } while (0)

// ---------------- prep: cast x -> bf16 AND transpose-cast W (one launch) ----------------
__global__ void mha_prep(const float* __restrict__ x, u16* __restrict__ xb,
                         const float* __restrict__ W0, const float* __restrict__ W1,
                         const float* __restrict__ W2, const float* __restrict__ W3,
                         u16* __restrict__ WtBase) {
    const int bid = blockIdx.x, tid = threadIdx.x;
    if (bid < 4096) {
        int i = (bid * 256 + tid) * 4;
        float4 v = *reinterpret_cast<const float4*>(x + i);
        ushort4 o;
        o.x = f2bf(v.x); o.y = f2bf(v.y); o.z = f2bf(v.z); o.w = f2bf(v.w);
        *reinterpret_cast<ushort4*>(xb + i) = o;
        return;
    }
    __shared__ float t[32][33];
    const int b2 = bid - 4096;
    const int mat = b2 >> 10, rem = b2 & 1023;
    const int cx = rem & 31, cy = rem >> 5;
    const float* W = (mat == 0) ? W0 : (mat == 1) ? W1 : (mat == 2) ? W2 : W3;
    u16* Wt = WtBase + (size_t)mat * DM * DM;
    const int c0 = cx * 32, r0 = cy * 32;
    const int tx = tid & 31, ty = tid >> 5;
#pragma unroll
    for (int i = ty; i < 32; i += 8)
        t[i][tx] = W[(size_t)(r0 + i) * DM + c0 + tx];
    __syncthreads();
#pragma unroll
    for (int i = ty; i < 32; i += 8)
        Wt[(size_t)(c0 + i) * DM + r0 + tx] = f2bf(t[tx][i]);
}

// ---------------- QKV GEMM v2 (r19): 128x192 tiles, 512 balanced blocks ----------------
__global__ __launch_bounds__(256, 2) void mha_gemm_qkv(const u16* __restrict__ xb, const u16* __restrict__ Wt,
                                                       const float* __restrict__ bq, const float* __restrict__ bk,
                                                       const float* __restrict__ bv, u16* __restrict__ qkv) {
    __shared__ __align__(16) char smem[81920];   // A[2][128][64] @0, B[2][192][64] @32768

    const int bid = blockIdx.x;
    const int bx = bid & 31, by = bid >> 5;      // 32 x 16
    const int m0 = bx * 128, n0g = by * 192;     // n0g in fused 0..3071

    const int tid = threadIdx.x;
    const int wave = tid >> 6, lane = tid & 63;
    const int lr = lane & 15, kg = lane >> 4;
    const int wr = wave >> 1, wc = wave & 1;     // wave owns 64x96

    auto STAGE = [&](int buf, int kt) {
#pragma unroll
        for (int i = 0; i < 4; ++i) {            // A: 16KB
            const int o = tid * 16 + i * 4096;
            const int r = o >> 7, slot = (o >> 4) & 7;
            gload_lds16(smem + buf * 16384 + o,
                        xb + (size_t)(m0 + r) * DM + kt * 64 + ((slot ^ (r & 7)) << 3));
        }
#pragma unroll
        for (int i = 0; i < 6; ++i) {            // B: 24KB (Wt rows n0g..n0g+191, fused)
            const int o = tid * 16 + i * 4096;
            const int r = o >> 7, slot = (o >> 4) & 7;
            gload_lds16(smem + 32768 + buf * 24576 + o,
                        Wt + (size_t)(n0g + r) * DM + kt * 64 + ((slot ^ (r & 7)) << 3));
        }
    };

    f32x4 acc[4][6] = {};
    STAGE(0, 0);
    for (int t = 0; t < 16; ++t) {
        if (t + 1 < 16) {
            STAGE((t + 1) & 1, t + 1);
            asm volatile("s_waitcnt vmcnt(10)" ::: "memory");
        } else {
            asm volatile("s_waitcnt vmcnt(0)" ::: "memory");
        }
        FENCE_BAR;
        const char* Ab = smem + (t & 1) * 16384;
        const char* Bb = smem + 32768 + (t & 1) * 24576;
#pragma unroll
        for (int ks = 0; ks < 2; ++ks) {
            s16x8 a[4], b[6];
#pragma unroll
            for (int m = 0; m < 4; ++m)
                a[m] = *reinterpret_cast<const s16x8*>(Ab + swz(wr * 64 + m * 16 + lr, ks * 64 + kg * 16));
#pragma unroll
            for (int n = 0; n < 6; ++n)
                b[n] = *reinterpret_cast<const s16x8*>(Bb + swz(wc * 96 + n * 16 + lr, ks * 64 + kg * 16));
#pragma unroll
            for (int m = 0; m < 4; ++m)
#pragma unroll
                for (int n = 0; n < 6; ++n)
                    acc[m][n] = __builtin_amdgcn_mfma_f32_16x16x32_bf16(a[m], b[n], acc[m][n], 0, 0, 0);
        }
        FENCE_BAR;
    }

    // direct-scatter epilogue; z resolved per 16-lane run (runs never cross 1024)
#pragma unroll
    for (int m = 0; m < 4; ++m)
#pragma unroll
        for (int n = 0; n < 6; ++n) {
            const int colg = n0g + wc * 96 + n * 16 + lr;    // 0..3071
            const int z = colg >> 10, coll = colg & 1023;
            const int h = coll >> 6, d = coll & 63;
            const float bv2 = ((z == 0) ? bq : (z == 1) ? bk : bv)[coll];
            const float scale = (z == 0) ? 0.125f * 1.44269504088896f : 1.0f;
            u16* Cout = qkv + (size_t)z * MM * DM;
#pragma unroll
            for (int j = 0; j < 4; ++j) {
                const int row = m0 + wr * 64 + m * 16 + kg * 4 + j;
                const int bb = row >> 11, s = row & (SS - 1);
                const float v = (acc[m][n][j] + bv2) * scale;
                if (z == 0) {
                    Cout[(((size_t)(bb * NH + h) * SS + s) * DK) + d] = f2bf(v);
                } else {
                    const int kt = s >> 6, r = s & 63;
                    const size_t tb = ((size_t)(bb * NH + h) * 32 + kt) * 4096;
                    const int bo = (z == 1) ? swz(r, d * 2)
                                            : swz(d, (r >> 1) * 4 + (r & 1) * 2);
                    Cout[tb + (bo >> 1)] = f2bf(v);
                }
            }
        }
}

// ---------------- gemm_out v2 (r20): 128x64 tiles, 512 blocks, counted-vmcnt dbuf ----------------
__global__ __launch_bounds__(256, 2) void mha_gemm_out(const u16* __restrict__ AO, const u16* __restrict__ WoT,
                                                       const float* __restrict__ bo, float* __restrict__ out) {
    __shared__ __align__(16) char smem[49152];   // A[2][128][64] @0, B[2][64][64] @32768

    const int bid = blockIdx.x;
    const int bx = bid & 31, by = bid >> 5;      // 32 x 16
    const int m0 = bx * 128, n0 = by * 64;

    const int tid = threadIdx.x;
    const int wave = tid >> 6, lane = tid & 63;
    const int lr = lane & 15, kg = lane >> 4;
    const int wr = wave >> 1, wc = wave & 1;     // wave owns 64x32

    auto STAGE = [&](int buf, int kt) {
#pragma unroll
        for (int i = 0; i < 4; ++i) {            // A: 16KB
            const int o = tid * 16 + i * 4096;
            const int r = o >> 7, slot = (o >> 4) & 7;
            gload_lds16(smem + buf * 16384 + o,
                        AO + (size_t)(m0 + r) * DM + kt * 64 + ((slot ^ (r & 7)) << 3));
        }
#pragma unroll
        for (int i = 0; i < 2; ++i) {            // B: 8KB
            const int o = tid * 16 + i * 4096;
            const int r = o >> 7, slot = (o >> 4) & 7;
            gload_lds16(smem + 32768 + buf * 8192 + o,
                        WoT + (size_t)(n0 + r) * DM + kt * 64 + ((slot ^ (r & 7)) << 3));
        }
    };

    f32x4 acc[4][2] = {};
    STAGE(0, 0);
    for (int t = 0; t < 16; ++t) {
        if (t + 1 < 16) {
            STAGE((t + 1) & 1, t + 1);
            asm volatile("s_waitcnt vmcnt(6)" ::: "memory");
        } else {
            asm volatile("s_waitcnt vmcnt(0)" ::: "memory");
        }
        FENCE_BAR;
        const char* Ab = smem + (t & 1) * 16384;
        const char* Bb = smem + 32768 + (t & 1) * 8192;
#pragma unroll
        for (int ks = 0; ks < 2; ++ks) {
            s16x8 a[4], b[2];
#pragma unroll
            for (int m = 0; m < 4; ++m)
                a[m] = *reinterpret_cast<const s16x8*>(Ab + swz(wr * 64 + m * 16 + lr, ks * 64 + kg * 16));
#pragma unroll
            for (int n = 0; n < 2; ++n)
                b[n] = *reinterpret_cast<const s16x8*>(Bb + swz(wc * 32 + n * 16 + lr, ks * 64 + kg * 16));
#pragma unroll
            for (int m = 0; m < 4; ++m)
#pragma unroll
                for (int n = 0; n < 2; ++n)
                    acc[m][n] = __builtin_amdgcn_mfma_f32_16x16x32_bf16(a[m], b[n], acc[m][n], 0, 0, 0);
        }
        FENCE_BAR;
    }

#pragma unroll
    for (int m = 0; m < 4; ++m)
#pragma unroll
        for (int n = 0; n < 2; ++n) {
            const int col = n0 + wc * 32 + n * 16 + lr;
            const float bv = bo[col];
#pragma unroll
            for (int j = 0; j < 4; ++j) {
                const int row = m0 + wr * 64 + m * 16 + kg * 4 + j;
                out[(size_t)row * DM + col] = acc[m][n][j] + bv;
            }
        }
}

// ---------------- flash attention v13: 4 waves x 32 q-rows (K/V read-redundancy halved) ----------------
// r21 analysis: attn is LDS-read bound — all 8 waves issued IDENTICAL K and V
// fragment reads (8x redundancy). 4 waves x 32 rows: each wave's K-frags feed
// 2 row-groups (4x reuse), V-frags feed both row-groups (2x reuse). Per
// block-iter LDS ops: 8x20 -> 4x28 (bytes -37%). Same 512-block PERM pairing
// (bid & bid+256 share a CU; extents sum to 34 iters). LDS 48KB, 2 blocks/CU.
__device__ const unsigned char PERM[16] = {15,14,13,12,11,10,9,8, 0,1,2,3,4,5,6,7};

__global__ __launch_bounds__(256, 2) void mha_attn(const u16* __restrict__ Qb, const u16* __restrict__ Kswz,
                                                   const u16* __restrict__ Vtswz, u16* __restrict__ AO) {
    // LDS: K dbuf 2x8KB @0 | V^T dbuf 2x8KB @16384 | P[4 waves][2 rg][2KB] @32768
    __shared__ __align__(16) char lds[49152];

    const int bid = blockIdx.x;
    const int bh  = bid & 31;
    const int qt  = PERM[bid >> 5];
    const int qb  = qt * 128;
    const int nkt = 2 * qt + 2;

    const int tid = threadIdx.x, w = tid >> 6, lane = tid & 63;
    const int lr = lane & 15, kg = lane >> 4;

    const u16* Qh = Qb + (size_t)bh * SS * DK;
    const char* Ktiles = (const char*)(Kswz  + (size_t)bh * 32 * 4096);
    const char* Vtiles = (const char*)(Vtswz + (size_t)bh * 32 * 4096);
    const int bb = bh >> 4, hh = bh & (NH - 1);
    char* psb = lds + 32768 + w * 4096;
    const int o = tid * 16;   // 256 thr x 16B x 2 rounds = 8KB per tile

    // Q fragments for both 16-row groups of this wave's 32 rows
    const int qr0 = qb + w * 32 + lr;
    const s16x8 qA0 = *reinterpret_cast<const s16x8*>(Qh + (size_t)qr0 * DK + kg * 8);
    const s16x8 qA1 = *reinterpret_cast<const s16x8*>(Qh + (size_t)qr0 * DK + 32 + kg * 8);
    const s16x8 qB0 = *reinterpret_cast<const s16x8*>(Qh + (size_t)(qr0 + 16) * DK + kg * 8);
    const s16x8 qB1 = *reinterpret_cast<const s16x8*>(Qh + (size_t)(qr0 + 16) * DK + 32 + kg * 8);

    f32x4 accA[4] = {}, accB[4] = {};
    float lpA = 0.f, lpB = 0.f;

    gload_lds16(lds + o,                Ktiles + o);
    gload_lds16(lds + o + 4096,         Ktiles + o + 4096);
    gload_lds16(lds + 16384 + o,        Vtiles + o);
    gload_lds16(lds + 16384 + o + 4096, Vtiles + o + 4096);

    for (int t = 0; t < nkt; ++t) {
        const int buf = t & 1;
        asm volatile("s_waitcnt vmcnt(0)" ::: "memory");
        __syncthreads();
        if (t + 1 < nkt) {
            const char* Kt = Ktiles + (t + 1) * 8192;
            const char* Vt = Vtiles + (t + 1) * 8192;
            char* kb2 = lds + (buf ^ 1) * 8192;
            char* vb2 = lds + 16384 + (buf ^ 1) * 8192;
            gload_lds16(kb2 + o,        Kt + o);
            gload_lds16(kb2 + o + 4096, Kt + o + 4096);
            gload_lds16(vb2 + o,        Vt + o);
            gload_lds16(vb2 + o + 4096, Vt + o + 4096);
        }
        const char* ksb = lds + buf * 8192;
        const char* vtb = lds + 16384 + buf * 8192;
        const int kb = t * 64;

        // swapped QK^T for both row-groups; K-frags loaded once, used 4x
        f32x4 sA[4], sB[4];
#pragma unroll
        for (int f = 0; f < 4; ++f) {
            const s16x8 kf0 = *reinterpret_cast<const s16x8*>(ksb + swz(f * 16 + lr, kg * 16));
            const s16x8 kf1 = *reinterpret_cast<const s16x8*>(ksb + swz(f * 16 + lr, 64 + kg * 16));
            f32x4 a = {}, b = {};
            a = __builtin_amdgcn_mfma_f32_16x16x32_bf16(kf0, qA0, a, 0, 0, 0);
            a = __builtin_amdgcn_mfma_f32_16x16x32_bf16(kf1, qA1, a, 0, 0, 0);
            b = __builtin_amdgcn_mfma_f32_16x16x32_bf16(kf0, qB0, b, 0, 0, 0);
            b = __builtin_amdgcn_mfma_f32_16x16x32_bf16(kf1, qB1, b, 0, 0, 0);
            sA[f] = a; sB[f] = b;
        }
#pragma unroll
        for (int f = 0; f < 4; ++f)
#pragma unroll
            for (int j = 0; j < 4; ++j) {
                sA[f][j] = __builtin_amdgcn_exp2f(sA[f][j]);
                sB[f][j] = __builtin_amdgcn_exp2f(sB[f][j]);
            }
        if (kb + 63 > qb + w * 32) {      // wave-uniform causal-frontier check
            const int qgA = qb + w * 32 + lr, qgB = qgA + 16;
#pragma unroll
            for (int f = 0; f < 4; ++f) {
                const int kc = kb + f * 16 + kg * 4;
#pragma unroll
                for (int j = 0; j < 4; ++j) {
                    if (kc + j > qgA) sA[f][j] = 0.f;
                    if (kc + j > qgB) sB[f][j] = 0.f;
                }
            }
        }
        // pack + store P for both row-groups; accumulate row sums
#pragma unroll
        for (int f = 0; f < 4; ++f) {
            u32x2 pa, pb;
            pa[0] = cvtpk(sA[f][0], sA[f][1]); pa[1] = cvtpk(sA[f][2], sA[f][3]);
            pb[0] = cvtpk(sB[f][0], sB[f][1]); pb[1] = cvtpk(sB[f][2], sB[f][3]);
            *reinterpret_cast<u32x2*>(psb + swz(lr, f * 32 + kg * 8)) = pa;
            *reinterpret_cast<u32x2*>(psb + 2048 + swz(lr, f * 32 + kg * 8)) = pb;
            lpA += (sA[f][0] + sA[f][1]) + (sA[f][2] + sA[f][3]);
            lpB += (sB[f][0] + sB[f][1]) + (sB[f][2] + sB[f][3]);
        }
        const s16x8 pA0 = *reinterpret_cast<const s16x8*>(psb + swz(lr, kg * 16));
        const s16x8 pA1 = *reinterpret_cast<const s16x8*>(psb + swz(lr, 64 + kg * 16));
        const s16x8 pB0 = *reinterpret_cast<const s16x8*>(psb + 2048 + swz(lr, kg * 16));
        const s16x8 pB1 = *reinterpret_cast<const s16x8*>(psb + 2048 + swz(lr, 64 + kg * 16));
        // PV: V-frags loaded once, used by both row-groups
#pragma unroll
        for (int db = 0; db < 4; ++db) {
            const s16x8 vf0 = *reinterpret_cast<const s16x8*>(vtb + swz(db * 16 + lr, kg * 16));
            const s16x8 vf1 = *reinterpret_cast<const s16x8*>(vtb + swz(db * 16 + lr, 64 + kg * 16));
            accA[db] = __builtin_amdgcn_mfma_f32_16x16x32_bf16(pA0, vf0, accA[db], 0, 0, 0);
            accA[db] = __builtin_amdgcn_mfma_f32_16x16x32_bf16(pA1, vf1, accA[db], 0, 0, 0);
            accB[db] = __builtin_amdgcn_mfma_f32_16x16x32_bf16(pB0, vf0, accB[db], 0, 0, 0);
            accB[db] = __builtin_amdgcn_mfma_f32_16x16x32_bf16(pB1, vf1, accB[db], 0, 0, 0);
        }
    }

    // complete row sums over the 4 kg-lanes holding each row
    lpA += __shfl_xor(lpA, 16, 64); lpA += __shfl_xor(lpA, 32, 64);
    lpB += __shfl_xor(lpB, 16, 64); lpB += __shfl_xor(lpB, 32, 64);

    float invA[4], invB[4];
#pragma unroll
    for (int j = 0; j < 4; ++j) {
        invA[j] = 1.0f / __shfl(lpA, kg * 4 + j, 64);
        invB[j] = 1.0f / __shfl(lpB, kg * 4 + j, 64);
    }
#pragma unroll
    for (int db = 0; db < 4; ++db) {
        const int d = db * 16 + lr;
#pragma unroll
        for (int j = 0; j < 4; ++j) {
            const int sA2 = qb + w * 32 + kg * 4 + j;
            AO[((size_t)(bb * SS + sA2)) * DM + hh * DK + d] = f2bf(accA[db][j] * invA[j]);
            AO[((size_t)(bb * SS + sA2 + 16)) * DM + hh * DK + d] = f2bf(accB[db][j] * invB[j]);
        }
    }
}

extern "C" void kernel_launch(void* const* d_in, const int* in_sizes, int n_in,
                              void* d_out, int out_size, void* d_ws, size_t ws_size,
                              hipStream_t stream) {
    const float* x  = (const float*)d_in[0];
    const float* Wq = (const float*)d_in[2];
    const float* bq = (const float*)d_in[3];
    const float* Wk = (const float*)d_in[4];
    const float* bk = (const float*)d_in[5];
    const float* Wv = (const float*)d_in[6];
    const float* bv = (const float*)d_in[7];
    const float* Wo = (const float*)d_in[8];
    const float* bo = (const float*)d_in[9];
    float* out = (float*)d_out;

    char* ws = (char*)d_ws;
    u16* xb  = (u16*)(ws);                       // 8 MB (dead after gemm_qkv)
    u16* Wt  = (u16*)(ws + ((size_t)8  << 20));  // 8 MB: Wq^T|Wk^T|Wv^T|Wo^T
    u16* qkv = (u16*)(ws + ((size_t)16 << 20));  // 24 MB: Q | K-swz tiles | V^T-swz tiles
    u16* AO  = (u16*)(ws + ((size_t)40 << 20));  // 8 MB

    mha_prep<<<dim3(8192), dim3(256), 0, stream>>>(x, xb, Wq, Wk, Wv, Wo, Wt);
    mha_gemm_qkv<<<dim3(512), dim3(256), 0, stream>>>(xb, Wt, bq, bk, bv, qkv);
    mha_attn<<<dim3(512), dim3(256), 0, stream>>>(qkv, qkv + (size_t)4194304, qkv + (size_t)8388608, AO);
    mha_gemm_out<<<dim3(512), dim3(256), 0, stream>>>(AO, Wt + (size_t)3 * DM * DM, bo, out);
}

// Round 23
// 95.202 us; speedup vs baseline: 1.0364x; 1.0364x over previous
//
#include <hip/hip_runtime.h>
#include <hip/hip_bf16.h>
#include <cstdint>
#include <cmath>

#define DM 1024
#define NH 16
#define DK 64
#define NB 2
#define SS 2048
#define MM (NB*SS)   // 4096 rows

typedef unsigned short u16;
typedef uint32_t u32;
typedef __attribute__((ext_vector_type(4))) float f32x4;
typedef __attribute__((ext_vector_type(8))) short s16x8;
typedef __attribute__((ext_vector_type(2))) uint32_t u32x2;

__device__ __forceinline__ u16 f2bf(float f) {
    __hip_bfloat16 h = __float2bfloat16(f);
    return __builtin_bit_cast(u16, h);
}

__device__ __forceinline__ u32 cvtpk(float a, float b) {
    u32 r;
    asm("v_cvt_pk_bf16_f32 %0, %1, %2" : "=v"(r) : "v"(a), "v"(b));
    return r;
}

__device__ __forceinline__ void gload_lds16(void* lds, const void* g) {
    __builtin_amdgcn_global_load_lds(
        (const __attribute__((address_space(1))) uint32_t*)g,
        (__attribute__((address_space(3))) uint32_t*)lds, 16, 0, 0);
}

// XOR-swizzled byte offset within a [rows][128B] LDS tile: 16B slot ^= row&7.
__device__ __forceinline__ int swz(int row, int cb) {
    return row * 128 + ((((cb) >> 4) ^ (row & 7)) << 4) + ((cb) & 15);
}

#define FENCE_BAR  do { __builtin_amdgcn_sched_barrier(0); \
                        __builtin_amdgcn_s_barrier();      \
                        __builtin_amdgcn_sched_barrier(0); } while (0)

// ---------------- prep: cast x -> bf16 AND transpose-cast W (one launch) ----------------
__global__ void mha_prep(const float* __restrict__ x, u16* __restrict__ xb,
                         const float* __restrict__ W0, const float* __restrict__ W1,
                         const float* __restrict__ W2, const float* __restrict__ W3,
                         u16* __restrict__ WtBase) {
    const int bid = blockIdx.x, tid = threadIdx.x;
    if (bid < 4096) {
        int i = (bid * 256 + tid) * 4;
        float4 v = *reinterpret_cast<const float4*>(x + i);
        ushort4 o;
        o.x = f2bf(v.x); o.y = f2bf(v.y); o.z = f2bf(v.z); o.w = f2bf(v.w);
        *reinterpret_cast<ushort4*>(xb + i) = o;
        return;
    }
    __shared__ float t[32][33];
    const int b2 = bid - 4096;
    const int mat = b2 >> 10, rem = b2 & 1023;
    const int cx = rem & 31, cy = rem >> 5;
    const float* W = (mat == 0) ? W0 : (mat == 1) ? W1 : (mat == 2) ? W2 : W3;
    u16* Wt = WtBase + (size_t)mat * DM * DM;
    const int c0 = cx * 32, r0 = cy * 32;
    const int tx = tid & 31, ty = tid >> 5;
#pragma unroll
    for (int i = ty; i < 32; i += 8)
        t[i][tx] = W[(size_t)(r0 + i) * DM + c0 + tx];
    __syncthreads();
#pragma unroll
    for (int i = ty; i < 32; i += 8)
        Wt[(size_t)(c0 + i) * DM + r0 + tx] = f2bf(t[tx][i]);
}

// ---------------- QKV GEMM v2 (r19): 128x192 tiles, 512 balanced blocks ----------------
__global__ __launch_bounds__(256, 2) void mha_gemm_qkv(const u16* __restrict__ xb, const u16* __restrict__ Wt,
                                                       const float* __restrict__ bq, const float* __restrict__ bk,
                                                       const float* __restrict__ bv, u16* __restrict__ qkv) {
    __shared__ __align__(16) char smem[81920];   // A[2][128][64] @0, B[2][192][64] @32768

    const int bid = blockIdx.x;
    const int bx = bid & 31, by = bid >> 5;      // 32 x 16
    const int m0 = bx * 128, n0g = by * 192;     // n0g in fused 0..3071

    const int tid = threadIdx.x;
    const int wave = tid >> 6, lane = tid & 63;
    const int lr = lane & 15, kg = lane >> 4;
    const int wr = wave >> 1, wc = wave & 1;     // wave owns 64x96

    auto STAGE = [&](int buf, int kt) {
#pragma unroll
        for (int i = 0; i < 4; ++i) {            // A: 16KB
            const int o = tid * 16 + i * 4096;
            const int r = o >> 7, slot = (o >> 4) & 7;
            gload_lds16(smem + buf * 16384 + o,
                        xb + (size_t)(m0 + r) * DM + kt * 64 + ((slot ^ (r & 7)) << 3));
        }
#pragma unroll
        for (int i = 0; i < 6; ++i) {            // B: 24KB (Wt rows n0g..n0g+191, fused)
            const int o = tid * 16 + i * 4096;
            const int r = o >> 7, slot = (o >> 4) & 7;
            gload_lds16(smem + 32768 + buf * 24576 + o,
                        Wt + (size_t)(n0g + r) * DM + kt * 64 + ((slot ^ (r & 7)) << 3));
        }
    };

    f32x4 acc[4][6] = {};
    STAGE(0, 0);
    for (int t = 0; t < 16; ++t) {
        if (t + 1 < 16) {
            STAGE((t + 1) & 1, t + 1);
            asm volatile("s_waitcnt vmcnt(10)" ::: "memory");
        } else {
            asm volatile("s_waitcnt vmcnt(0)" ::: "memory");
        }
        FENCE_BAR;
        const char* Ab = smem + (t & 1) * 16384;
        const char* Bb = smem + 32768 + (t & 1) * 24576;
#pragma unroll
        for (int ks = 0; ks < 2; ++ks) {
            s16x8 a[4], b[6];
#pragma unroll
            for (int m = 0; m < 4; ++m)
                a[m] = *reinterpret_cast<const s16x8*>(Ab + swz(wr * 64 + m * 16 + lr, ks * 64 + kg * 16));
#pragma unroll
            for (int n = 0; n < 6; ++n)
                b[n] = *reinterpret_cast<const s16x8*>(Bb + swz(wc * 96 + n * 16 + lr, ks * 64 + kg * 16));
#pragma unroll
            for (int m = 0; m < 4; ++m)
#pragma unroll
                for (int n = 0; n < 6; ++n)
                    acc[m][n] = __builtin_amdgcn_mfma_f32_16x16x32_bf16(a[m], b[n], acc[m][n], 0, 0, 0);
        }
        FENCE_BAR;
    }

    // direct-scatter epilogue; z resolved per 16-lane run (runs never cross 1024)
#pragma unroll
    for (int m = 0; m < 4; ++m)
#pragma unroll
        for (int n = 0; n < 6; ++n) {
            const int colg = n0g + wc * 96 + n * 16 + lr;    // 0..3071
            const int z = colg >> 10, coll = colg & 1023;
            const int h = coll >> 6, d = coll & 63;
            const float bv2 = ((z == 0) ? bq : (z == 1) ? bk : bv)[coll];
            const float scale = (z == 0) ? 0.125f * 1.44269504088896f : 1.0f;
            u16* Cout = qkv + (size_t)z * MM * DM;
#pragma unroll
            for (int j = 0; j < 4; ++j) {
                const int row = m0 + wr * 64 + m * 16 + kg * 4 + j;
                const int bb = row >> 11, s = row & (SS - 1);
                const float v = (acc[m][n][j] + bv2) * scale;
                if (z == 0) {
                    Cout[(((size_t)(bb * NH + h) * SS + s) * DK) + d] = f2bf(v);
                } else {
                    const int kt = s >> 6, r = s & 63;
                    const size_t tb = ((size_t)(bb * NH + h) * 32 + kt) * 4096;
                    const int bo = (z == 1) ? swz(r, d * 2)
                                            : swz(d, (r >> 1) * 4 + (r & 1) * 2);
                    Cout[tb + (bo >> 1)] = f2bf(v);
                }
            }
        }
}

// ---------------- gemm_out v2 (r20): 128x64 tiles, 512 blocks, counted-vmcnt dbuf ----------------
__global__ __launch_bounds__(256, 2) void mha_gemm_out(const u16* __restrict__ AO, const u16* __restrict__ WoT,
                                                       const float* __restrict__ bo, float* __restrict__ out) {
    __shared__ __align__(16) char smem[49152];   // A[2][128][64] @0, B[2][64][64] @32768

    const int bid = blockIdx.x;
    const int bx = bid & 31, by = bid >> 5;      // 32 x 16
    const int m0 = bx * 128, n0 = by * 64;

    const int tid = threadIdx.x;
    const int wave = tid >> 6, lane = tid & 63;
    const int lr = lane & 15, kg = lane >> 4;
    const int wr = wave >> 1, wc = wave & 1;     // wave owns 64x32

    auto STAGE = [&](int buf, int kt) {
#pragma unroll
        for (int i = 0; i < 4; ++i) {            // A: 16KB
            const int o = tid * 16 + i * 4096;
            const int r = o >> 7, slot = (o >> 4) & 7;
            gload_lds16(smem + buf * 16384 + o,
                        AO + (size_t)(m0 + r) * DM + kt * 64 + ((slot ^ (r & 7)) << 3));
        }
#pragma unroll
        for (int i = 0; i < 2; ++i) {            // B: 8KB
            const int o = tid * 16 + i * 4096;
            const int r = o >> 7, slot = (o >> 4) & 7;
            gload_lds16(smem + 32768 + buf * 8192 + o,
                        WoT + (size_t)(n0 + r) * DM + kt * 64 + ((slot ^ (r & 7)) << 3));
        }
    };

    f32x4 acc[4][2] = {};
    STAGE(0, 0);
    for (int t = 0; t < 16; ++t) {
        if (t + 1 < 16) {
            STAGE((t + 1) & 1, t + 1);
            asm volatile("s_waitcnt vmcnt(6)" ::: "memory");
        } else {
            asm volatile("s_waitcnt vmcnt(0)" ::: "memory");
        }
        FENCE_BAR;
        const char* Ab = smem + (t & 1) * 16384;
        const char* Bb = smem + 32768 + (t & 1) * 8192;
#pragma unroll
        for (int ks = 0; ks < 2; ++ks) {
            s16x8 a[4], b[2];
#pragma unroll
            for (int m = 0; m < 4; ++m)
                a[m] = *reinterpret_cast<const s16x8*>(Ab + swz(wr * 64 + m * 16 + lr, ks * 64 + kg * 16));
#pragma unroll
            for (int n = 0; n < 2; ++n)
                b[n] = *reinterpret_cast<const s16x8*>(Bb + swz(wc * 32 + n * 16 + lr, ks * 64 + kg * 16));
#pragma unroll
            for (int m = 0; m < 4; ++m)
#pragma unroll
                for (int n = 0; n < 2; ++n)
                    acc[m][n] = __builtin_amdgcn_mfma_f32_16x16x32_bf16(a[m], b[n], acc[m][n], 0, 0, 0);
        }
        FENCE_BAR;
    }

#pragma unroll
    for (int m = 0; m < 4; ++m)
#pragma unroll
        for (int n = 0; n < 2; ++n) {
            const int col = n0 + wc * 32 + n * 16 + lr;
            const float bv = bo[col];
#pragma unroll
            for (int j = 0; j < 4; ++j) {
                const int row = m0 + wr * 64 + m * 16 + kg * 4 + j;
                out[(size_t)row * DM + col] = acc[m][n][j] + bv;
            }
        }
}

// ---------------- flash attention v12 (r21-verified best): non-split, co-CU pairing ----------------
// 512 blocks (16 qt x 32 bh) of 512 thr = exactly 2 blocks/CU, whole grid
// co-resident. Blocks bid and bid+256 share a CU; PERM[j]+PERM[j+8]=15 makes
// every co-CU pair run exactly 34 k-iters. bh = bid&31 keeps head->XCD pinning.
__device__ const unsigned char PERM[16] = {15,14,13,12,11,10,9,8, 0,1,2,3,4,5,6,7};

__global__ __launch_bounds__(512, 4) void mha_attn(const u16* __restrict__ Qb, const u16* __restrict__ Kswz,
                                                   const u16* __restrict__ Vtswz, u16* __restrict__ AO) {
    // LDS: K dbuf 2x8KB @0 | V^T dbuf 2x8KB @16384 | Ps[8 waves][2KB] @32768
    __shared__ __align__(16) char lds[49152];

    const int bid = blockIdx.x;
    const int bh  = bid & 31;
    const int qt  = PERM[bid >> 5];
    const int qb  = qt * 128;
    const int nkt = 2 * qt + 2;

    const int tid = threadIdx.x, w = tid >> 6, lane = tid & 63;
    const int lr = lane & 15, kg = lane >> 4;

    const u16* Qh = Qb + (size_t)bh * SS * DK;
    const char* Ktiles = (const char*)(Kswz  + (size_t)bh * 32 * 4096);
    const char* Vtiles = (const char*)(Vtswz + (size_t)bh * 32 * 4096);
    const int bb = bh >> 4, hh = bh & (NH - 1);
    char* psb = lds + 32768 + w * 2048;
    const int o = tid * 16;

    const int qrow = qb + w * 16 + lr;
    const s16x8 qf0 = *reinterpret_cast<const s16x8*>(Qh + (size_t)qrow * DK + kg * 8);
    const s16x8 qf1 = *reinterpret_cast<const s16x8*>(Qh + (size_t)qrow * DK + 32 + kg * 8);
    f32x4 accO[4] = {};
    float lp = 0.f;

    gload_lds16(lds + o,         Ktiles + o);
    gload_lds16(lds + 16384 + o, Vtiles + o);

    for (int t = 0; t < nkt; ++t) {
        const int buf = t & 1;
        asm volatile("s_waitcnt vmcnt(0)" ::: "memory");
        __syncthreads();
        if (t + 1 < nkt) {
            gload_lds16(lds + (buf ^ 1) * 8192 + o,         Ktiles + (t + 1) * 8192 + o);
            gload_lds16(lds + 16384 + (buf ^ 1) * 8192 + o, Vtiles + (t + 1) * 8192 + o);
        }
        const char* ksb = lds + buf * 8192;
        const char* vtb = lds + 16384 + buf * 8192;
        const int kb = t * 64;

        // swapped QK^T: lane holds P[q=lr][k=f*16+kg*4+j]
        f32x4 sc[4];
#pragma unroll
        for (int f = 0; f < 4; ++f) {
            s16x8 kf0 = *reinterpret_cast<const s16x8*>(ksb + swz(f * 16 + lr, kg * 16));
            s16x8 kf1 = *reinterpret_cast<const s16x8*>(ksb + swz(f * 16 + lr, 64 + kg * 16));
            f32x4 s = {};
            s = __builtin_amdgcn_mfma_f32_16x16x32_bf16(kf0, qf0, s, 0, 0, 0);
            s = __builtin_amdgcn_mfma_f32_16x16x32_bf16(kf1, qf1, s, 0, 0, 0);
            sc[f] = s;
        }
#pragma unroll
        for (int f = 0; f < 4; ++f)
#pragma unroll
            for (int j = 0; j < 4; ++j)
                sc[f][j] = __builtin_amdgcn_exp2f(sc[f][j]);
        if (kb + 63 > qb + w * 16) {      // wave-uniform causal-frontier check
            const int qg = qb + w * 16 + lr;
#pragma unroll
            for (int f = 0; f < 4; ++f) {
                const int kc = kb + f * 16 + kg * 4;
#pragma unroll
                for (int j = 0; j < 4; ++j)
                    if (kc + j > qg) sc[f][j] = 0.f;
            }
        }
        float fs0 = 0.f, fs1 = 0.f;
#pragma unroll
        for (int f = 0; f < 4; ++f) {
            u32x2 pp;
            pp[0] = cvtpk(sc[f][0], sc[f][1]);
            pp[1] = cvtpk(sc[f][2], sc[f][3]);
            *reinterpret_cast<u32x2*>(psb + swz(lr, f * 32 + kg * 8)) = pp;
            const float s01 = sc[f][0] + sc[f][1], s23 = sc[f][2] + sc[f][3];
            if (f & 1) fs1 += s01 + s23; else fs0 += s01 + s23;
        }
        lp += fs0 + fs1;

        const s16x8 pf0 = *reinterpret_cast<const s16x8*>(psb + swz(lr, kg * 16));
        const s16x8 pf1 = *reinterpret_cast<const s16x8*>(psb + swz(lr, 64 + kg * 16));
#pragma unroll
        for (int db = 0; db < 4; ++db) {
            s16x8 vf0 = *reinterpret_cast<const s16x8*>(vtb + swz(db * 16 + lr, kg * 16));
            s16x8 vf1 = *reinterpret_cast<const s16x8*>(vtb + swz(db * 16 + lr, 64 + kg * 16));
            accO[db] = __builtin_amdgcn_mfma_f32_16x16x32_bf16(pf0, vf0, accO[db], 0, 0, 0);
            accO[db] = __builtin_amdgcn_mfma_f32_16x16x32_bf16(pf1, vf1, accO[db], 0, 0, 0);
        }
    }

    // complete row sums over the 4 kg-lanes holding row q=lr
    lp += __shfl_xor(lp, 16, 64);
    lp += __shfl_xor(lp, 32, 64);

    float inv[4];
#pragma unroll
    for (int j = 0; j < 4; ++j)
        inv[j] = 1.0f / __shfl(lp, kg * 4 + j, 64);
#pragma unroll
    for (int db = 0; db < 4; ++db) {
        const int d = db * 16 + lr;
#pragma unroll
        for (int j = 0; j < 4; ++j) {
            const int s = qb + w * 16 + kg * 4 + j;
            AO[((size_t)(bb * SS + s)) * DM + hh * DK + d] = f2bf(accO[db][j] * inv[j]);
        }
    }
}

extern "C" void kernel_launch(void* const* d_in, const int* in_sizes, int n_in,
                              void* d_out, int out_size, void* d_ws, size_t ws_size,
                              hipStream_t stream) {
    const float* x  = (const float*)d_in[0];
    const float* Wq = (const float*)d_in[2];
    const float* bq = (const float*)d_in[3];
    const float* Wk = (const float*)d_in[4];
    const float* bk = (const float*)d_in[5];
    const float* Wv = (const float*)d_in[6];
    const float* bv = (const float*)d_in[7];
    const float* Wo = (const float*)d_in[8];
    const float* bo = (const float*)d_in[9];
    float* out = (float*)d_out;

    char* ws = (char*)d_ws;
    u16* xb  = (u16*)(ws);                       // 8 MB (dead after gemm_qkv)
    u16* Wt  = (u16*)(ws + ((size_t)8  << 20));  // 8 MB: Wq^T|Wk^T|Wv^T|Wo^T
    u16* qkv = (u16*)(ws + ((size_t)16 << 20));  // 24 MB: Q | K-swz tiles | V^T-swz tiles
    u16* AO  = (u16*)(ws + ((size_t)40 << 20));  // 8 MB

    mha_prep<<<dim3(8192), dim3(256), 0, stream>>>(x, xb, Wq, Wk, Wv, Wo, Wt);
    mha_gemm_qkv<<<dim3(512), dim3(256), 0, stream>>>(xb, Wt, bq, bk, bv, qkv);
    mha_attn<<<dim3(512), dim3(512), 0, stream>>>(qkv, qkv + (size_t)4194304, qkv + (size_t)8388608, AO);
    mha_gemm_out<<<dim3(512), dim3(256), 0, stream>>>(AO, Wt + (size_t)3 * DM * DM, bo, out);
}